// Round 5
// baseline (874.896 us; speedup 1.0000x reference)
//
#include <hip/hip_runtime.h>
#include <hip/hip_bf16.h>
#include <stdint.h>

// Problem constants: B=8, S=2048, D_IN=4096, D_OUT=4096
#define MROWS 16384
#define DIN   4096
#define DOUT  4096
#define KEFF  1024

typedef __attribute__((ext_vector_type(8))) __bf16 bf16x8;
typedef __attribute__((ext_vector_type(4))) float f32x4;

#define AS1 __attribute__((address_space(1)))
#define AS3 __attribute__((address_space(3)))

__device__ __forceinline__ uint32_t f2bf_rne(float f) {
  union { float f; uint32_t u; } v; v.f = f;
  uint32_t u = v.u;
  return (u + 0x7fffu + ((u >> 16) & 1u)) >> 16;
}

// Merged gather: 2-of-8 (positions 0,2 per group of 8) for x then w.
__global__ void venom_gather_all(const float* __restrict__ x,
                                 const float* __restrict__ w,
                                 uint2* __restrict__ xg, uint2* __restrict__ wg) {
  const int PX = MROWS * (DIN / 16);
  const int PW = DOUT * (DIN / 16);
  int stride = gridDim.x * blockDim.x;
  for (int i = blockIdx.x * blockDim.x + threadIdx.x; i < PX + PW; i += stride) {
    const float* src; uint2* dst; int idx;
    if (i < PX) { src = x; dst = xg; idx = i; }
    else        { src = w; dst = wg; idx = i - PX; }
    const float4* p = reinterpret_cast<const float4*>(src) + (size_t)idx * 4;
    float4 a = p[0];
    float4 b = p[2];
    uint2 r;
    r.x = f2bf_rne(a.x) | (f2bf_rne(a.z) << 16);
    r.y = f2bf_rne(b.x) | (f2bf_rne(b.z) << 16);
    dst[idx] = r;
  }
}

// ---------------- ABLATION: template<V> persistent 256x256 GEMM ----------------
// V0 = control (round-4 counted-vmcnt ring)       [correct output, runs LAST]
// V1 = __syncthreads() drain everywhere           [correct output]
// V2 = no in-loop staging (stale LDS)             [garbage output, overwritten]
// V3 = no per-phase ds_reads (stale fragments)    [garbage output, overwritten]
#define BM 256
#define BN 256
#define BK 64
#define NT (KEFF / BK)   // 16
#define TPB 4

__device__ __forceinline__ int swz_off(int R, int lg) {
  int sr = R >> 1;
  return sr * 128 + (((((R & 1) << 2) | lg) ^ (sr & 7)) << 4);
}

template <int V>
__global__ __launch_bounds__(512, 2) void venom_gemm(
    const __bf16* __restrict__ A, const __bf16* __restrict__ Bm,
    const float* __restrict__ bias, float* __restrict__ C) {
  constexpr bool STAGE_EN = (V != 2);
  constexpr bool DSREAD   = (V != 3);
  constexpr bool RING     = (V != 1);

  __shared__ __bf16 As[2][2][128 * 64];
  __shared__ __bf16 Bs[2][2][128 * 64];

  int nwg = gridDim.x;
  int cpx = nwg >> 3;
  int bid = blockIdx.x;
  int swz = (bid & 7) * cpx + (bid >> 3);
  int mblk = swz >> 2;
  int ngrp = swz & 3;

  int t = threadIdx.x;
  int wid = t >> 6, l = t & 63;
  int wr = wid >> 2, wc = wid & 3;
  int lr = l & 15, lg = l >> 4;

  const __bf16* Ag = A + (size_t)(mblk * BM) * KEFF;

  float biasr[TPB][4];
  #pragma unroll
  for (int j = 0; j < TPB; ++j)
    #pragma unroll
    for (int ni = 0; ni < 4; ++ni)
      biasr[j][ni] = bias[(ngrp * TPB + j) * BN + wc * 64 + ni * 16 + lr];

  f32x4 acc[8][4] = {};

  auto stage_half = [&](int j2, int kt2, int kh) {
    const int buf = kt2 & 1;
    const __bf16* Bg = Bm + (size_t)((ngrp * TPB + j2) * BN) * KEFF;
    const int k0 = kt2 * BK + kh * 32;
    #pragma unroll
    for (int i = 0; i < 2; ++i) {
      int e = i * 512 + t;
      int sr = e >> 3;
      int s = (e & 7) ^ (sr & 7);
      int row = sr * 2 + (s >> 2);
      int koff = (s & 3) * 8;
      __builtin_amdgcn_global_load_lds(
          (const AS1 uint32_t*)(Ag + (size_t)row * KEFF + k0 + koff),
          ((AS3 uint32_t*)&As[buf][kh][0]) + e * 4, 16, 0, 0);
      __builtin_amdgcn_global_load_lds(
          (const AS1 uint32_t*)(Bg + (size_t)row * KEFF + k0 + koff),
          ((AS3 uint32_t*)&Bs[buf][kh][0]) + e * 4, 16, 0, 0);
    }
  };

  // Prologue
  stage_half(0, 0, 0);
  stage_half(0, 0, 1);
  if constexpr (V == 2) {  // define buf1 too (it is never re-staged in V2)
    stage_half(0, 1, 0);
    stage_half(0, 1, 1);
  }
  if constexpr (RING) {
    if constexpr (V == 2) asm volatile("s_waitcnt vmcnt(0)" ::: "memory");
    else                  asm volatile("s_waitcnt vmcnt(4)" ::: "memory");
    __builtin_amdgcn_s_barrier();
  } else {
    __syncthreads();
  }

  bf16x8 af[4], bfrag[4];
  if constexpr (!DSREAD) {  // V3: load fragments once; phases reuse them
    #pragma unroll
    for (int mi = 0; mi < 4; ++mi)
      af[mi] = *(const bf16x8*)((const char*)&As[0][0][0] +
                 swz_off(wr * 128 + mi * 16 + lr, lg));
    #pragma unroll
    for (int ni = 0; ni < 4; ++ni)
      bfrag[ni] = *(const bf16x8*)((const char*)&Bs[0][0][0] +
                   swz_off(wc * 64 + ni * 16 + lr, lg));
  }

  #pragma unroll
  for (int j = 0; j < TPB; ++j) {
    #pragma unroll 1
    for (int kt = 0; kt < NT; ++kt) {
      const int cur = kt & 1;
      const bool last_it = (j == TPB - 1) && (kt == NT - 1);
      const int j2  = (kt < NT - 1) ? j : j + 1;
      const int kt2 = (kt < NT - 1) ? kt + 1 : 0;

      #pragma unroll
      for (int ph = 0; ph < 4; ++ph) {
        const int mh = ph & 1, kh = ph >> 1;
        if constexpr (DSREAD) {
          const char* aB = (const char*)&As[cur][kh][0];
          #pragma unroll
          for (int mi = 0; mi < 4; ++mi)
            af[mi] = *(const bf16x8*)(aB + swz_off(wr * 128 + mh * 64 + mi * 16 + lr, lg));
          if (mh == 0) {
            const char* bB = (const char*)&Bs[cur][kh][0];
            #pragma unroll
            for (int ni = 0; ni < 4; ++ni)
              bfrag[ni] = *(const bf16x8*)(bB + swz_off(wc * 64 + ni * 16 + lr, lg));
          }
        }
        if (mh == 0) {
          if constexpr (STAGE_EN) { if (!last_it) stage_half(j2, kt2, kh); }
        }

        if constexpr (RING) __builtin_amdgcn_s_barrier(); else __syncthreads();
        __builtin_amdgcn_s_setprio(1);
        #pragma unroll
        for (int mi = 0; mi < 4; ++mi)
          #pragma unroll
          for (int ni = 0; ni < 4; ++ni)
            acc[mh * 4 + mi][ni] = __builtin_amdgcn_mfma_f32_16x16x32_bf16(
                af[mi], bfrag[ni], acc[mh * 4 + mi][ni], 0, 0, 0);
        __builtin_amdgcn_s_setprio(0);

        if (ph == 1) {
          if constexpr (RING) {
            if (!last_it) asm volatile("s_waitcnt vmcnt(4)" ::: "memory");
            else          asm volatile("s_waitcnt vmcnt(0)" ::: "memory");
            __builtin_amdgcn_s_barrier();
          } else __syncthreads();
        } else if (ph == 3) {
          if (!last_it) {
            if constexpr (RING) {
              asm volatile("s_waitcnt vmcnt(4)" ::: "memory");
              __builtin_amdgcn_s_barrier();
            } else __syncthreads();
          }
        } else {
          if constexpr (RING) __builtin_amdgcn_s_barrier(); else __syncthreads();
        }
      }
    }

    // Epilogue for tile j
    {
      int colbase = (ngrp * TPB + j) * BN + wc * 64;
      int rowbase = mblk * BM + wr * 128;
      #pragma unroll
      for (int mh = 0; mh < 2; ++mh)
        #pragma unroll
        for (int mi = 0; mi < 4; ++mi) {
          int row0 = rowbase + mh * 64 + mi * 16 + lg * 4;
          #pragma unroll
          for (int ni = 0; ni < 4; ++ni) {
            int col = colbase + ni * 16 + lr;
            f32x4 cv = acc[mh * 4 + mi][ni];
            #pragma unroll
            for (int jj = 0; jj < 4; ++jj)
              C[(size_t)(row0 + jj) * DOUT + col] = cv[jj] + biasr[j][ni];
          }
        }
      #pragma unroll
      for (int q = 0; q < 8; ++q)
        #pragma unroll
        for (int ni = 0; ni < 4; ++ni)
          acc[q][ni] = (f32x4){0.f, 0.f, 0.f, 0.f};
    }
  }
}

// Fallback
__global__ void venom_naive(const float* __restrict__ x, const float* __restrict__ w,
                            const float* __restrict__ bias, float* __restrict__ out) {
  size_t total = (size_t)MROWS * DOUT;
  size_t stride = (size_t)gridDim.x * blockDim.x;
  for (size_t idx = (size_t)blockIdx.x * blockDim.x + threadIdx.x; idx < total;
       idx += stride) {
    int m = (int)(idx / DOUT), n = (int)(idx % DOUT);
    const float* xr = x + (size_t)m * DIN;
    const float* wr = w + (size_t)n * DIN;
    float s = 0.f;
    for (int g = 0; g < DIN / 8; ++g)
      s += xr[g * 8] * wr[g * 8] + xr[g * 8 + 2] * wr[g * 8 + 2];
    out[idx] = s + bias[n];
  }
}

extern "C" void kernel_launch(void* const* d_in, const int* in_sizes, int n_in,
                              void* d_out, int out_size, void* d_ws, size_t ws_size,
                              hipStream_t stream) {
  const float* x    = (const float*)d_in[0];
  const float* wgt  = (const float*)d_in[1];
  const float* bias = (const float*)d_in[2];
  float* out = (float*)d_out;

  const size_t xg_bytes = (size_t)MROWS * KEFF * 2;
  const size_t wg_bytes = (size_t)DOUT * KEFF * 2;

  if (ws_size < xg_bytes + wg_bytes) {
    venom_naive<<<2048, 256, 0, stream>>>(x, wgt, bias, out);
    return;
  }

  uint32_t* xg = (uint32_t*)d_ws;
  uint32_t* wg = (uint32_t*)((char*)d_ws + xg_bytes);

  venom_gather_all<<<2048, 256, 0, stream>>>(x, wgt, (uint2*)xg, (uint2*)wg);

  const int grid = (MROWS / BM) * (DOUT / BN / TPB);  // 256
  // Diagnostics first (V2/V3 write garbage, V1 correct), control V0 LAST so
  // the final d_out is correct and deterministic.
  venom_gemm<2><<<grid, 512, 0, stream>>>((const __bf16*)xg, (const __bf16*)wg, bias, out);
  venom_gemm<3><<<grid, 512, 0, stream>>>((const __bf16*)xg, (const __bf16*)wg, bias, out);
  venom_gemm<1><<<grid, 512, 0, stream>>>((const __bf16*)xg, (const __bf16*)wg, bias, out);
  venom_gemm<0><<<grid, 512, 0, stream>>>((const __bf16*)xg, (const __bf16*)wg, bias, out);
}

// Round 6
// 308.862 us; speedup vs baseline: 2.8326x; 2.8326x over previous
//
#include <hip/hip_runtime.h>
#include <hip/hip_bf16.h>
#include <stdint.h>

// Problem constants: B=8, S=2048, D_IN=4096, D_OUT=4096
#define MROWS 16384
#define DIN   4096
#define DOUT  4096
#define KEFF  1024

typedef __attribute__((ext_vector_type(8))) __bf16 bf16x8;
typedef __attribute__((ext_vector_type(4))) float f32x4;
typedef __attribute__((ext_vector_type(4))) int   i32x4;

#define AS1 __attribute__((address_space(1)))
#define AS3 __attribute__((address_space(3)))

__device__ __forceinline__ uint32_t f2bf_rne(float f) {
  union { float f; uint32_t u; } v; v.f = f;
  uint32_t u = v.u;
  return (u + 0x7fffu + ((u >> 16) & 1u)) >> 16;
}

// Merged gather: 2-of-8 (positions 0,2 per group of 8) for x then w.
__global__ void venom_gather_all(const float* __restrict__ x,
                                 const float* __restrict__ w,
                                 uint2* __restrict__ xg, uint2* __restrict__ wg) {
  const int PX = MROWS * (DIN / 16);
  const int PW = DOUT * (DIN / 16);
  int stride = gridDim.x * blockDim.x;
  for (int i = blockIdx.x * blockDim.x + threadIdx.x; i < PX + PW; i += stride) {
    const float* src; uint2* dst; int idx;
    if (i < PX) { src = x; dst = xg; idx = i; }
    else        { src = w; dst = wg; idx = i - PX; }
    const float4* p = reinterpret_cast<const float4*>(src) + (size_t)idx * 4;
    float4 a = p[0];
    float4 b = p[2];
    uint2 r;
    r.x = f2bf_rne(a.x) | (f2bf_rne(a.z) << 16);
    r.y = f2bf_rne(b.x) | (f2bf_rne(b.z) << 16);
    dst[idx] = r;
  }
}

// ---- persistent 256x256 bf16 GEMM: double-buffered frags, counted lgkm/vm ----
#define BM 256
#define BN 256
#define BK 64
#define NT (KEFF / BK)   // 16
#define TPB 4
#define HALF_BYTES 16384  // one 128x64 bf16 half-tile

__device__ __forceinline__ uint32_t swz_off(int R, int lg) {
  int sr = R >> 1;
  return (uint32_t)(sr * 128 + (((((R & 1) << 2) | lg) ^ (sr & 7)) << 4));
}

__device__ __forceinline__ bf16x8 asbf(i32x4 v) {
  union { i32x4 i; bf16x8 b; } u; u.i = v; return u.b;
}

#define DSR(dst, a) asm volatile("ds_read_b128 %0, %1" : "=v"(dst) : "v"(a))
#define WAIT_LGKM(n) do { asm volatile("s_waitcnt lgkmcnt(" #n ")" ::: "memory"); \
                          __builtin_amdgcn_sched_barrier(0); } while (0)
#define WAIT_VM(n) asm volatile("s_waitcnt vmcnt(" #n ")" ::: "memory")
#define BAR() __builtin_amdgcn_s_barrier()

__global__ __launch_bounds__(512, 2) void venom_gemm_dbf(
    const __bf16* __restrict__ A, const __bf16* __restrict__ Bm,
    const float* __restrict__ bias, float* __restrict__ C) {
  __shared__ __bf16 As[2][2][128 * 64];
  __shared__ __bf16 Bs[2][2][128 * 64];

  // grid = 256; XCD-bijective swizzle
  int nwg = gridDim.x;
  int cpx = nwg >> 3;
  int bid = blockIdx.x;
  int swz = (bid & 7) * cpx + (bid >> 3);
  int mblk = swz >> 2;
  int ngrp = swz & 3;

  int t = threadIdx.x;
  int wid = t >> 6, l = t & 63;
  int wr = wid >> 2, wc = wid & 3;   // wave owns 128x64 of C
  int lr = l & 15, lg = l >> 4;

  const __bf16* Ag = A + (size_t)(mblk * BM) * KEFF;

  uint32_t asB = (uint32_t)(uintptr_t)(AS3 __bf16*)&As[0][0][0];
  uint32_t bsB = (uint32_t)(uintptr_t)(AS3 __bf16*)&Bs[0][0][0];

  f32x4 acc[8][4] = {};
  i32x4 af0[4], af1[4], bf0[4], bf1[4];

  auto issueA = [&](i32x4 (&d)[4], int buf, int kh, int mh) {
    uint32_t base = asB + (uint32_t)((buf * 2 + kh) * HALF_BYTES);
    #pragma unroll
    for (int mi = 0; mi < 4; ++mi)
      DSR(d[mi], base + swz_off(wr * 128 + mh * 64 + mi * 16 + lr, lg));
  };
  auto issueB = [&](i32x4 (&d)[4], int buf, int kh) {
    uint32_t base = bsB + (uint32_t)((buf * 2 + kh) * HALF_BYTES);
    #pragma unroll
    for (int ni = 0; ni < 4; ++ni)
      DSR(d[ni], base + swz_off(wc * 64 + ni * 16 + lr, lg));
  };
  auto mfma16 = [&](int rb, i32x4 (&a)[4], i32x4 (&b)[4]) {
    __builtin_amdgcn_s_setprio(1);
    #pragma unroll
    for (int mi = 0; mi < 4; ++mi)
      #pragma unroll
      for (int ni = 0; ni < 4; ++ni)
        acc[rb + mi][ni] = __builtin_amdgcn_mfma_f32_16x16x32_bf16(
            asbf(a[mi]), asbf(b[ni]), acc[rb + mi][ni], 0, 0, 0);
    __builtin_amdgcn_s_setprio(0);
  };

  // Stage one k-half (4 global_load_lds per thread). Linear LDS dest,
  // inverse-swizzled global source (rule #21).
  auto stage_half = [&](int j2, int kt2, int kh) {
    const int buf = kt2 & 1;
    const __bf16* Bg = Bm + (size_t)((ngrp * TPB + j2) * BN) * KEFF;
    const int k0 = kt2 * BK + kh * 32;
    #pragma unroll
    for (int i = 0; i < 2; ++i) {
      int e = i * 512 + t;
      int sr = e >> 3;
      int s = (e & 7) ^ (sr & 7);
      int row = sr * 2 + (s >> 2);
      int koff = (s & 3) * 8;
      __builtin_amdgcn_global_load_lds(
          (const AS1 uint32_t*)(Ag + (size_t)row * KEFF + k0 + koff),
          ((AS3 uint32_t*)&As[buf][kh][0]) + e * 4, 16, 0, 0);
      __builtin_amdgcn_global_load_lds(
          (const AS1 uint32_t*)(Bg + (size_t)row * KEFF + k0 + koff),
          ((AS3 uint32_t*)&Bs[buf][kh][0]) + e * 4, 16, 0, 0);
    }
  };

  // Prologue: stage tile 0 (kh0 then kh1); wait kh0 only; issue ph0 frags.
  stage_half(0, 0, 0);
  stage_half(0, 0, 1);
  WAIT_VM(4);
  BAR();
  issueA(af0, 0, 0, 0);
  issueB(bf0, 0, 0);
  // invariants entering each tile: lgkm outstanding = 8 (af0,bf0); vm = 4 (kh1)

  #pragma unroll
  for (int j = 0; j < TPB; ++j) {
    #pragma unroll 1
    for (int kt = 0; kt < NT; ++kt) {
      const int cur = kt & 1;
      const bool last = (j == TPB - 1) && (kt == NT - 1);
      const int j2  = (kt < NT - 1) ? j : j + 1;
      const int kt2 = (kt < NT - 1) ? kt + 1 : 0;
      const int nbuf = kt2 & 1;

      // ---- ph0: MFMA(mh0,kh0) on af0/bf0; prefetch af1; stage next kh0 ----
      issueA(af1, cur, 0, 1);
      if (!last) stage_half(j2, kt2, 0);
      BAR();
      WAIT_LGKM(4);            // af0,bf0 done; af1 in flight
      mfma16(0, af0, bf0);
      if (last) WAIT_VM(0); else WAIT_VM(4);   // this tile's kh1 arrived
      BAR();

      // ---- ph1: MFMA(mh1,kh0) on af1/bf0; prefetch af0(kh1), bf1(kh1) ----
      issueA(af0, cur, 1, 0);
      issueB(bf1, cur, 1);
      BAR();
      WAIT_LGKM(8);            // af1 done; af0',bf1 in flight
      mfma16(4, af1, bf0);
      BAR();

      // ---- ph2: MFMA(mh0,kh1) on af0/bf1; prefetch af1(kh1); stage next kh1 ----
      issueA(af1, cur, 1, 1);
      if (!last) stage_half(j2, kt2, 1);
      BAR();
      WAIT_LGKM(4);            // af0',bf1 done; af1' in flight
      mfma16(0, af0, bf1);
      BAR();

      // ---- ph3: MFMA(mh1,kh1) on af1/bf1 ----
      WAIT_LGKM(0);
      mfma16(4, af1, bf1);
      if (last) WAIT_VM(0); else WAIT_VM(4);   // next tile's kh0 arrived
      BAR();
      if (!last) {             // issue next tile's ph0 frags
        issueA(af0, nbuf, 0, 0);
        issueB(bf0, nbuf, 0);
      }
    }

    // Epilogue for tile j. No LDS; overlaps in-flight staging.
    {
      int colbase = (ngrp * TPB + j) * BN + wc * 64;
      int rowbase = mblk * BM + wr * 128;
      #pragma unroll
      for (int ni = 0; ni < 4; ++ni) {
        int col = colbase + ni * 16 + lr;
        float bv = bias[col];
        #pragma unroll
        for (int mh = 0; mh < 2; ++mh)
          #pragma unroll
          for (int mi = 0; mi < 4; ++mi) {
            int row0 = rowbase + mh * 64 + mi * 16 + lg * 4;
            f32x4 cv = acc[mh * 4 + mi][ni];
            #pragma unroll
            for (int jj = 0; jj < 4; ++jj)
              C[(size_t)(row0 + jj) * DOUT + col] = cv[jj] + bv;
          }
      }
      #pragma unroll
      for (int q = 0; q < 8; ++q)
        #pragma unroll
        for (int ni = 0; ni < 4; ++ni)
          acc[q][ni] = (f32x4){0.f, 0.f, 0.f, 0.f};
    }
  }
}

// Fallback
__global__ void venom_naive(const float* __restrict__ x, const float* __restrict__ w,
                            const float* __restrict__ bias, float* __restrict__ out) {
  size_t total = (size_t)MROWS * DOUT;
  size_t stride = (size_t)gridDim.x * blockDim.x;
  for (size_t idx = (size_t)blockIdx.x * blockDim.x + threadIdx.x; idx < total;
       idx += stride) {
    int m = (int)(idx / DOUT), n = (int)(idx % DOUT);
    const float* xr = x + (size_t)m * DIN;
    const float* wr = w + (size_t)n * DIN;
    float s = 0.f;
    for (int g = 0; g < DIN / 8; ++g)
      s += xr[g * 8] * wr[g * 8] + xr[g * 8 + 2] * wr[g * 8 + 2];
    out[idx] = s + bias[n];
  }
}

extern "C" void kernel_launch(void* const* d_in, const int* in_sizes, int n_in,
                              void* d_out, int out_size, void* d_ws, size_t ws_size,
                              hipStream_t stream) {
  const float* x    = (const float*)d_in[0];
  const float* wgt  = (const float*)d_in[1];
  const float* bias = (const float*)d_in[2];
  float* out = (float*)d_out;

  const size_t xg_bytes = (size_t)MROWS * KEFF * 2;
  const size_t wg_bytes = (size_t)DOUT * KEFF * 2;

  if (ws_size < xg_bytes + wg_bytes) {
    venom_naive<<<2048, 256, 0, stream>>>(x, wgt, bias, out);
    return;
  }

  uint32_t* xg = (uint32_t*)d_ws;
  uint32_t* wg = (uint32_t*)((char*)d_ws + xg_bytes);

  venom_gather_all<<<2048, 256, 0, stream>>>(x, wgt, (uint2*)xg, (uint2*)wg);

  venom_gemm_dbf<<<(MROWS / BM) * (DOUT / BN / TPB), 512, 0, stream>>>(
      (const __bf16*)xg, (const __bf16*)wg, bias, out);
}

// Round 7
// 287.028 us; speedup vs baseline: 3.0481x; 1.0761x over previous
//
#include <hip/hip_runtime.h>
#include <hip/hip_bf16.h>
#include <stdint.h>

// Problem constants: B=8, S=2048, D_IN=4096, D_OUT=4096
#define MROWS 16384
#define DIN   4096
#define DOUT  4096
#define KEFF  1024

typedef __attribute__((ext_vector_type(8))) __bf16 bf16x8;
typedef __attribute__((ext_vector_type(4))) float f32x4;

#define AS1 __attribute__((address_space(1)))
#define AS3 __attribute__((address_space(3)))

__device__ __forceinline__ uint32_t f2bf_rne(float f) {
  union { float f; uint32_t u; } v; v.f = f;
  uint32_t u = v.u;
  return (u + 0x7fffu + ((u >> 16) & 1u)) >> 16;
}

// Merged gather: 2-of-8 (positions 0,2 per group of 8) for x then w.
__global__ void venom_gather_all(const float* __restrict__ x,
                                 const float* __restrict__ w,
                                 uint2* __restrict__ xg, uint2* __restrict__ wg) {
  const int PX = MROWS * (DIN / 16);
  const int PW = DOUT * (DIN / 16);
  int stride = gridDim.x * blockDim.x;
  for (int i = blockIdx.x * blockDim.x + threadIdx.x; i < PX + PW; i += stride) {
    const float* src; uint2* dst; int idx;
    if (i < PX) { src = x; dst = xg; idx = i; }
    else        { src = w; dst = wg; idx = i - PX; }
    const float4* p = reinterpret_cast<const float4*>(src) + (size_t)idx * 4;
    float4 a = p[0];
    float4 b = p[2];
    uint2 r;
    r.x = f2bf_rne(a.x) | (f2bf_rne(a.z) << 16);
    r.y = f2bf_rne(b.x) | (f2bf_rne(b.z) << 16);
    dst[idx] = r;
  }
}

// --- persistent 256x256 bf16 GEMM, 3-half-tile-deep counted-vmcnt pipeline ---
// A = Xg [MROWS][KEFF] bf16 row-major, B = Wg [DOUT][KEFF] bf16 row-major (B^T).
// C[m][n] = sum_k A[m][k]*B[n][k] + bias[n], fp32 row-major.
#define BM 256
#define BN 256
#define BK 64
#define NT (KEFF / BK)   // 16
#define TPB 4
#define LTOT (NT * TPB)  // 64 K-tile iterations per block

// LDS half-tile: [128 superrows][128B]; superrow sr = rows 2sr,2sr+1 (64B each),
// 8x16B slots XOR-swizzled by (sr&7).
__device__ __forceinline__ int swz_off(int R, int lg) {
  int sr = R >> 1;
  return sr * 128 + (((((R & 1) << 2) | lg) ^ (sr & 7)) << 4);
}

#define WAIT_VM(n) asm volatile("s_waitcnt vmcnt(" #n ")" ::: "memory")
#define BAR() __builtin_amdgcn_s_barrier()

__global__ __launch_bounds__(512, 2) void venom_gemm_p3(
    const __bf16* __restrict__ A, const __bf16* __restrict__ Bm,
    const float* __restrict__ bias, float* __restrict__ C) {
  // [tile-parity][k-half][16KB] for A and B: 128 KiB, 4 half-slots each
  __shared__ __bf16 As[2][2][128 * 64];
  __shared__ __bf16 Bs[2][2][128 * 64];

  // grid = 256; XCD-bijective swizzle
  int nwg = gridDim.x;
  int cpx = nwg >> 3;
  int bid = blockIdx.x;
  int swz = (bid & 7) * cpx + (bid >> 3);
  int mblk = swz >> 2;
  int ngrp = swz & 3;

  int t = threadIdx.x;
  int wid = t >> 6, l = t & 63;
  int wr = wid >> 2, wc = wid & 3;   // 2x4 wave grid; wave owns 128x64 of C
  int lr = l & 15, lg = l >> 4;

  const __bf16* Ag = A + (size_t)(mblk * BM) * KEFF;

  float biasr[TPB][4];
  #pragma unroll
  for (int j = 0; j < TPB; ++j)
    #pragma unroll
    for (int ni = 0; ni < 4; ++ni)
      biasr[j][ni] = bias[(ngrp * TPB + j) * BN + wc * 64 + ni * 16 + lr];

  f32x4 acc[8][4] = {};

  // Stage one k-half of global K-tile L2 (4 global_load_lds per thread).
  // Linear LDS dest, inverse-swizzled global source (rule #21).
  auto stage_half = [&](int L2, int kh) {
    const int buf = L2 & 1;          // NT even -> parity == kt parity
    const int j2 = L2 >> 4;
    const int kt2 = L2 & (NT - 1);
    const __bf16* Bg = Bm + (size_t)((ngrp * TPB + j2) * BN) * KEFF;
    const int k0 = kt2 * BK + kh * 32;
    #pragma unroll
    for (int i = 0; i < 2; ++i) {
      int e = i * 512 + t;
      int sr = e >> 3;
      int s = (e & 7) ^ (sr & 7);
      int row = sr * 2 + (s >> 2);
      int koff = (s & 3) * 8;
      __builtin_amdgcn_global_load_lds(
          (const AS1 uint32_t*)(Ag + (size_t)row * KEFF + k0 + koff),
          ((AS3 uint32_t*)&As[buf][kh][0]) + e * 4, 16, 0, 0);
      __builtin_amdgcn_global_load_lds(
          (const AS1 uint32_t*)(Bg + (size_t)row * KEFF + k0 + koff),
          ((AS3 uint32_t*)&Bs[buf][kh][0]) + e * 4, 16, 0, 0);
    }
  };

  // Prologue: 3 half-tiles in flight (m201 depth), drain only the first.
  stage_half(0, 0);
  stage_half(0, 1);
  stage_half(1, 0);
  WAIT_VM(8);
  BAR();

  bf16x8 bfrag[4];

  #pragma unroll
  for (int j = 0; j < TPB; ++j) {
    #pragma unroll 1
    for (int kt = 0; kt < NT; ++kt) {
      const int L = j * NT + kt;
      const int cur = kt & 1;

      // Phases (mh,kh): (0,0),(1,0),(0,1),(1,1).
      // Stage schedule (1.5 K-tiles ahead): ph0 -> (L+1,kh1); ph2 -> (L+2,kh0).
      // Steady waits: ph1-end vm(8) gates (L,kh1); ph3-end vm(8) gates (L+1,kh0).
      #pragma unroll
      for (int ph = 0; ph < 4; ++ph) {
        const int mh = ph & 1, kh = ph >> 1;
        const char* aB = (const char*)&As[cur][kh][0];
        bf16x8 af[4];
        #pragma unroll
        for (int mi = 0; mi < 4; ++mi)
          af[mi] = *(const bf16x8*)(aB + swz_off(wr * 128 + mh * 64 + mi * 16 + lr, lg));
        if (mh == 0) {
          const char* bB = (const char*)&Bs[cur][kh][0];
          #pragma unroll
          for (int ni = 0; ni < 4; ++ni)
            bfrag[ni] = *(const bf16x8*)(bB + swz_off(wc * 64 + ni * 16 + lr, lg));
          if (kh == 0) { if (L + 1 < LTOT) stage_half(L + 1, 1); }
          else         { if (L + 2 < LTOT) stage_half(L + 2, 0); }
        }

        BAR();
        __builtin_amdgcn_s_setprio(1);
        #pragma unroll
        for (int mi = 0; mi < 4; ++mi)
          #pragma unroll
          for (int ni = 0; ni < 4; ++ni)
            acc[mh * 4 + mi][ni] = __builtin_amdgcn_mfma_f32_16x16x32_bf16(
                af[mi], bfrag[ni], acc[mh * 4 + mi][ni], 0, 0, 0);
        __builtin_amdgcn_s_setprio(0);

        if (ph == 1) {
          // Gate this tile's kh1 (issued at ph0 of L-1).
          if (L <= LTOT - 2) WAIT_VM(8);
          else               WAIT_VM(0);   // L=63: drain all
          BAR();
        } else if (ph == 3) {
          // Gate next tile's kh0 (issued at ph2 of L-1).
          if (L <= LTOT - 3)      WAIT_VM(8);
          else if (L == LTOT - 2) WAIT_VM(4);
          else                    WAIT_VM(0);
          BAR();
        } else {
          BAR();
        }
      }
    }

    // Epilogue for tile j (static biasr index; no LDS -> overlaps staging).
    {
      int colbase = (ngrp * TPB + j) * BN + wc * 64;
      int rowbase = mblk * BM + wr * 128;
      #pragma unroll
      for (int mh = 0; mh < 2; ++mh)
        #pragma unroll
        for (int mi = 0; mi < 4; ++mi) {
          int row0 = rowbase + mh * 64 + mi * 16 + lg * 4;
          #pragma unroll
          for (int ni = 0; ni < 4; ++ni) {
            int col = colbase + ni * 16 + lr;
            f32x4 cv = acc[mh * 4 + mi][ni];
            #pragma unroll
            for (int jj = 0; jj < 4; ++jj)
              C[(size_t)(row0 + jj) * DOUT + col] = cv[jj] + biasr[j][ni];
          }
        }
      #pragma unroll
      for (int q = 0; q < 8; ++q)
        #pragma unroll
        for (int ni = 0; ni < 4; ++ni)
          acc[q][ni] = (f32x4){0.f, 0.f, 0.f, 0.f};
    }
  }
}

// Fallback
__global__ void venom_naive(const float* __restrict__ x, const float* __restrict__ w,
                            const float* __restrict__ bias, float* __restrict__ out) {
  size_t total = (size_t)MROWS * DOUT;
  size_t stride = (size_t)gridDim.x * blockDim.x;
  for (size_t idx = (size_t)blockIdx.x * blockDim.x + threadIdx.x; idx < total;
       idx += stride) {
    int m = (int)(idx / DOUT), n = (int)(idx % DOUT);
    const float* xr = x + (size_t)m * DIN;
    const float* wr = w + (size_t)n * DIN;
    float s = 0.f;
    for (int g = 0; g < DIN / 8; ++g)
      s += xr[g * 8] * wr[g * 8] + xr[g * 8 + 2] * wr[g * 8 + 2];
    out[idx] = s + bias[n];
  }
}

extern "C" void kernel_launch(void* const* d_in, const int* in_sizes, int n_in,
                              void* d_out, int out_size, void* d_ws, size_t ws_size,
                              hipStream_t stream) {
  const float* x    = (const float*)d_in[0];
  const float* wgt  = (const float*)d_in[1];
  const float* bias = (const float*)d_in[2];
  float* out = (float*)d_out;

  const size_t xg_bytes = (size_t)MROWS * KEFF * 2;
  const size_t wg_bytes = (size_t)DOUT * KEFF * 2;

  if (ws_size < xg_bytes + wg_bytes) {
    venom_naive<<<2048, 256, 0, stream>>>(x, wgt, bias, out);
    return;
  }

  uint32_t* xg = (uint32_t*)d_ws;
  uint32_t* wg = (uint32_t*)((char*)d_ws + xg_bytes);

  venom_gather_all<<<2048, 256, 0, stream>>>(x, wgt, (uint2*)xg, (uint2*)wg);

  venom_gemm_p3<<<(MROWS / BM) * (DOUT / BN / TPB), 512, 0, stream>>>(
      (const __bf16*)xg, (const __bf16*)wg, bias, out);
}